// Round 4
// baseline (358.407 us; speedup 1.0000x reference)
//
#include <hip/hip_runtime.h>
#include <math.h>

typedef unsigned short u16;
typedef unsigned int u32;

// ---------------------------------------------------------------------------
// Layouts (ws in f32 units):
//   x1p [b][n1=128][34][34] bf16  @ 0          (4,734,976 u)
//   x0p [b][c=64][34][34]  f32    @ 4,734,976  (4,734,976 u)
//   x2  [b][32][32][128]   f32    @ 4,734,976  (over dead x0p, 8,388,608 u)
//   partial @ 0 (over dead x1p), h @ 2,000,000, w1p @ 13,200,000 (+18,432)
// Peak 52.9 MB (R1 proved 64 MB usable).
// ---------------------------------------------------------------------------
#define PL 1156            // 34*34
#define X0P_OFF 4734976
#define X2_OFF  4734976
#define H_OFF   2000000
#define W1P_OFF 13200000

__device__ __forceinline__ float bfu(u16 u) {
    union { u32 i; float f; } c; c.i = ((u32)u) << 16; return c.f;
}
__device__ __forceinline__ u16 f2bf(float f) {
    union { float f; u32 i; } c; c.f = f;
    u32 r = c.i + 0x7fffu + ((c.i >> 16) & 1u);   // RNE
    return (u16)(r >> 16);
}

// ---------------- halo zero: borders of all planes ---------------------------
__global__ void halo_zero(float* __restrict__ x0p, u16* __restrict__ x1p) {
    int t = blockIdx.x * 256 + threadIdx.x;       // 12288*132 = 1,622,016
    int p = t / 132;
    int i = t - p * 132;
    int row, cc;
    if (i < 68)       { row = (i >= 34) ? 33 : 0; cc = (i >= 34) ? i - 34 : i; }
    else if (i < 100) { row = i - 67; cc = 0; }
    else              { row = i - 99; cc = 33; }
    int off = row * 34 + cc;
    if (p < 4096) x0p[p * PL + off] = 0.f;
    else          x1p[(p - 4096) * PL + off] = 0;
}

// ---------------- w1 repack: w1p[tap*16+f][q][i0] ---------------------------
__global__ void w1_pack(const float* __restrict__ cw1, float* __restrict__ w1p) {
    int t = blockIdx.x * blockDim.x + threadIdx.x;   // 18432
    int i0 = t & 15, q = (t >> 4) & 7, tf = t >> 7;
    w1p[t] = cw1[tf * 128 + i0 + 16 * q];
}

// ---------------- Layer 0: dense conv 3 -> 64, write padded planes ----------
__global__ __launch_bounds__(256) void l0_kernel(const float* __restrict__ in,
    const float* __restrict__ w, const float* __restrict__ bias, float* __restrict__ x0p) {
    int bi = blockIdx.x;
    int cib = bi & 3, rb = (bi >> 2) & 3, b = bi >> 4;
    int t = threadIdx.x, lane = t & 63, wv = t >> 6;
    int col = lane & 31;
    int row = rb * 8 + wv * 2 + (lane >> 5);
    int n0 = cib * 16;

    float acc[16];
#pragma unroll
    for (int k = 0; k < 16; ++k) acc[k] = bias[n0 + k];

    for (int ky = 0; ky < 3; ++ky) {
        int yy = row + ky - 1;
        for (int kx = 0; kx < 3; ++kx) {
            int xx = col + kx - 1;
            if ((unsigned)yy < 32u && (unsigned)xx < 32u) {
                const float* pb = in + ((b * 32 + yy) * 32 + xx) * 3;
                float p0 = pb[0], p1 = pb[1], p2 = pb[2];
                const float* wb = w + (ky * 3 + kx) * 192 + n0;
#pragma unroll
                for (int c = 0; c < 3; ++c) {
                    float pc = (c == 0) ? p0 : ((c == 1) ? p1 : p2);
#pragma unroll
                    for (int k = 0; k < 16; ++k) acc[k] += pc * wb[c * 64 + k];
                }
            }
        }
    }
    float* ob = x0p + (size_t)(b * 64 + n0) * PL + (row + 1) * 34 + col + 1;
#pragma unroll
    for (int k = 0; k < 16; ++k) ob[k * PL] = fmaxf(acc[k], 0.f);
}

// ---------------- Layer 1: fan-in 16, LDS-staged, 64 outs/thread ------------
template <int I0B>
__device__ __forceinline__ void l1_body(const float* x0s, const float* __restrict__ w1p,
                                        int orow, int col, float (&acc)[8][8]) {
    for (int dy = 0; dy < 3; ++dy) {
        for (int dx = 0; dx < 3; ++dx) {
            int px = (orow + dy) * 34 + col + dx;
            const float* xs = x0s + px;
            const float* wt = w1p + (dy * 3 + dx) * 16 * 128 + I0B;
#pragma unroll 1
            for (int ci = 0; ci < 4; ++ci) {
                const float* xc = xs + ci * (16 * 204);
#pragma unroll
                for (int m = 0; m < 4; ++m) {
                    float a[8];
#pragma unroll
                    for (int ii = 0; ii < 8; ++ii) {
                        const int i0 = I0B + ii;
                        const int r = (i0 >= 3) ? (i0 - 3 + m) : ((m <= i0) ? m : (12 + m));
                        a[ii] = xc[r * 204];
                    }
                    const float* wr = wt + (4 * ci + m) * 128;
#pragma unroll
                    for (int q = 0; q < 8; ++q) {
                        float4 wa = *(const float4*)(wr + q * 16);
                        float4 wb = *(const float4*)(wr + q * 16 + 4);
                        acc[0][q] += a[0] * wa.x; acc[1][q] += a[1] * wa.y;
                        acc[2][q] += a[2] * wa.z; acc[3][q] += a[3] * wa.w;
                        acc[4][q] += a[4] * wb.x; acc[5][q] += a[5] * wb.y;
                        acc[6][q] += a[6] * wb.z; acc[7][q] += a[7] * wb.w;
                    }
                }
            }
        }
    }
}

__global__ __launch_bounds__(256) void l1_kernel(const float* __restrict__ x0p,
    const float* __restrict__ w1p, const float* __restrict__ cb1, u16* __restrict__ x1p) {
    __shared__ float x0s[64 * 204];     // [c][6*34] f32, 52,224 B
    int bi = blockIdx.x;
    int rb = bi & 7, b = bi >> 3;
    int r0 = rb * 4;
    int t = threadIdx.x;

    {   // stage rows r0..r0+5 of all 64 planes; 64 chunks x 102 u64
        const char* src = (const char*)(x0p + (size_t)b * 64 * PL + r0 * 34);
        for (int u = t; u < 6528; u += 256) {
            int c = u / 102;
            int e = u - c * 102;
            uint2 v = *(const uint2*)(src + c * 4624 + e * 8);
            *(uint2*)((char*)x0s + c * 816 + e * 8) = v;
        }
    }
    __syncthreads();

    int col = t & 31, orow = (t >> 5) & 3;
    int h = __builtin_amdgcn_readfirstlane(t >> 7);
    int h8 = h * 8;

    float acc[8][8];
#pragma unroll
    for (int ii = 0; ii < 8; ++ii)
#pragma unroll
        for (int q = 0; q < 8; ++q) acc[ii][q] = cb1[h8 + ii + 16 * q];

    if (h) l1_body<8>(x0s, w1p, orow, col, acc);
    else   l1_body<0>(x0s, w1p, orow, col, acc);

    int prow = r0 + orow + 1;
    u16* ob = x1p + (size_t)b * 128 * PL + prow * 34 + col + 1;
#pragma unroll
    for (int ii = 0; ii < 8; ++ii)
#pragma unroll
        for (int q = 0; q < 8; ++q)
            ob[(h8 + ii + 16 * q) * PL] = f2bf(fmaxf(acc[ii][q], 0.f));
}

// ---------------- Layer 2: fan-in 32, LDS-staged, 64 outs/thread ------------
__global__ __launch_bounds__(256) void l2_kernel(const u16* __restrict__ x1p,
    const float* __restrict__ cw2, const float* __restrict__ cb2, float* __restrict__ x2) {
    __shared__ u16 x1s[128 * 204];      // [ch][6*34] bf16, 52,224 B
    int bi = blockIdx.x;
    int rb = bi & 7, b = bi >> 3;
    int r0 = rb * 4;
    int t = threadIdx.x;

    {   // stage rows r0..r0+5 of all 128 planes; 128 chunks x 51 u64
        const char* src = (const char*)(x1p + (size_t)b * 128 * PL + r0 * 34);
        for (int u = t; u < 6528; u += 256) {
            int c = u / 51;
            int e = u - c * 51;
            uint2 v = *(const uint2*)(src + c * 2312 + e * 8);
            *(uint2*)((char*)x1s + c * 408 + e * 8) = v;
        }
    }
    __syncthreads();

    int col = t & 31, orow = (t >> 5) & 3;
    int h = __builtin_amdgcn_readfirstlane(t >> 7);

    float4 acc[16];
#pragma unroll
    for (int q = 0; q < 16; ++q) acc[q] = *(const float4*)(cb2 + h * 64 + q * 4);

    for (int dy = 0; dy < 3; ++dy) {
        for (int dx = 0; dx < 3; ++dx) {
            int px = (orow + dy) * 34 + col + dx;
            const u16* xs = x1s + px;
            const float* wt = cw2 + (dy * 3 + dx) * 4096 + h * 64;
#pragma unroll 2
            for (int j = 0; j < 32; ++j) {
                const u16* xj = xs + j * 816;
                float a0 = bfu(xj[0]);
                float a1 = bfu(xj[204]);
                float a2 = bfu(xj[408]);
                float a3 = bfu(xj[612]);
                const float* wr = wt + j * 128;
#pragma unroll
                for (int q = 0; q < 16; ++q) {
                    float4 wq = *(const float4*)(wr + q * 4);
                    acc[q].x += a0 * wq.x; acc[q].y += a1 * wq.y;
                    acc[q].z += a2 * wq.z; acc[q].w += a3 * wq.w;
                }
            }
        }
    }
    int row = r0 + orow;
    float* ob = x2 + (size_t)b * 131072 + (row * 32 + col) * 128 + h * 64;
#pragma unroll
    for (int q = 0; q < 16; ++q) {
        float4 o;
        o.x = fmaxf(acc[q].x, 0.f); o.y = fmaxf(acc[q].y, 0.f);
        o.z = fmaxf(acc[q].z, 0.f); o.w = fmaxf(acc[q].w, 0.f);
        *(float4*)(ob + q * 4) = o;
    }
}

// ---------------- Dense 1 + reduce + dense 2 ---------------------------------
#define D1_NB 512
#define D1_KPB 256
#define D1_SUB 128
__global__ __launch_bounds__(320) void d1_kernel(const float* __restrict__ x2,
                                                 const float* __restrict__ dw1,
                                                 float* __restrict__ partial) {
    __shared__ float XT[D1_SUB][65];
    int t = threadIdx.x;
    int b = t & 63;
    int jg = __builtin_amdgcn_readfirstlane(t >> 6);
    float acc[10];
#pragma unroll
    for (int jj = 0; jj < 10; ++jj) acc[jj] = 0.f;

    for (int r = 0; r < D1_KPB / D1_SUB; ++r) {
        int k0 = blockIdx.x * D1_KPB + r * D1_SUB;
        __syncthreads();
        for (int u = t; u < 64 * D1_SUB; u += 320) {
            int bb = u >> 7;
            int i  = u & (D1_SUB - 1);
            XT[i][bb] = x2[bb * 131072 + k0 + i];
        }
        __syncthreads();
        for (int k = 0; k < D1_SUB; ++k) {
            float xv = XT[k][b];
            const float* wr = dw1 + (k0 + k) * 50 + jg * 10;
#pragma unroll
            for (int jj = 0; jj < 10; ++jj)
                acc[jj] += xv * wr[jj];
        }
    }
    float* po = partial + blockIdx.x * 3200 + jg * 640 + b;
#pragma unroll
    for (int jj = 0; jj < 10; ++jj) po[jj * 64] = acc[jj];
}

__global__ void d1_reduce(const float* __restrict__ partial, float* __restrict__ h) {
    int t = blockIdx.x * blockDim.x + threadIdx.x;
    if (t >= 3200) return;
    float s0 = 0.f, s1 = 0.f, s2 = 0.f, s3 = 0.f;
    for (int cb = 0; cb < D1_NB; cb += 4) {
        s0 += partial[(cb + 0) * 3200 + t];
        s1 += partial[(cb + 1) * 3200 + t];
        s2 += partial[(cb + 2) * 3200 + t];
        s3 += partial[(cb + 3) * 3200 + t];
    }
    h[t] = (s0 + s1) + (s2 + s3);
}

__global__ void d2_kernel(const float* __restrict__ h, const float* __restrict__ db1,
                          const float* __restrict__ dw2, const float* __restrict__ db2,
                          float* __restrict__ out) {
    int b = threadIdx.x;
    float a[10];
#pragma unroll
    for (int j = 0; j < 10; ++j) a[j] = db2[j];
    for (int i = 0; i < 50; ++i) {
        float v = fmaxf(h[i * 64 + b] + db1[i], 0.f);
#pragma unroll
        for (int j = 0; j < 10; ++j) a[j] += v * dw2[i * 10 + j];
    }
    float mx = a[0];
#pragma unroll
    for (int j = 1; j < 10; ++j) mx = fmaxf(mx, a[j]);
    float s = 0.f;
#pragma unroll
    for (int j = 0; j < 10; ++j) { a[j] = expf(a[j] - mx); s += a[j]; }
    float inv = 1.f / s;
#pragma unroll
    for (int j = 0; j < 10; ++j) out[b * 10 + j] = a[j] * inv;
}

// -----------------------------------------------------------------------------
extern "C" void kernel_launch(void* const* d_in, const int* in_sizes, int n_in,
                              void* d_out, int out_size, void* d_ws, size_t ws_size,
                              hipStream_t stream) {
    const float* inputs = (const float*)d_in[0];
    const float* cw0 = (const float*)d_in[1];
    const float* cb0 = (const float*)d_in[2];
    const float* cw1 = (const float*)d_in[3];
    const float* cb1 = (const float*)d_in[4];
    const float* cw2 = (const float*)d_in[5];
    const float* cb2 = (const float*)d_in[6];
    const float* dw1 = (const float*)d_in[7];
    const float* db1 = (const float*)d_in[8];
    const float* dw2 = (const float*)d_in[9];
    const float* db2 = (const float*)d_in[10];
    float* out = (float*)d_out;

    float* ws = (float*)d_ws;
    u16*   x1p     = (u16*)ws;
    float* x0p     = ws + X0P_OFF;
    float* x2      = ws + X2_OFF;
    float* partial = ws;
    float* h       = ws + H_OFF;
    float* w1p     = ws + W1P_OFF;

    halo_zero<<<6336, 256, 0, stream>>>(x0p, x1p);
    w1_pack<<<72, 256, 0, stream>>>(cw1, w1p);
    l0_kernel<<<1024, 256, 0, stream>>>(inputs, cw0, cb0, x0p);
    l1_kernel<<<512, 256, 0, stream>>>(x0p, w1p, cb1, x1p);
    l2_kernel<<<512, 256, 0, stream>>>(x1p, cw2, cb2, x2);
    d1_kernel<<<D1_NB, 320, 0, stream>>>(x2, dw1, partial);
    d1_reduce<<<13, 256, 0, stream>>>(partial, h);
    d2_kernel<<<1, 64, 0, stream>>>(h, db1, dw2, db2, out);
}

// Round 5
// 215.457 us; speedup vs baseline: 1.6635x; 1.6635x over previous
//
#include <hip/hip_runtime.h>
#include <math.h>

typedef unsigned short u16;
typedef unsigned int u32;
typedef __attribute__((ext_vector_type(8))) short short8v;    // 8 bf16 (4 VGPR)
typedef __attribute__((ext_vector_type(4))) unsigned short ushort4v;
typedef __attribute__((ext_vector_type(4))) float f32x4;

// ---------------------------------------------------------------------------
// ws layout (f32 units):
//   x1pn [b][34][34][128] bf16 @ 0          (4,734,976 f32)
//   x0pn [b][34][34][64]  bf16 @ 4,734,976  (2,367,488 f32)
//   x2b  [b][32][32][128] bf16 @ 7,102,464  (4,194,304 f32)
//   partial @ 0 (over dead x1pn, 1,638,400), h @ 2,000,000
//   w1p bf16 @ 11,300,000 (40,960 u16), w2p bf16 @ 11,330,000 (36,864 u16)
// Peak ~45.4 MB.
// ---------------------------------------------------------------------------
#define X0PN_OFF 4734976
#define X2B_OFF  7102464
#define H_OFF    2000000
#define W1P_OFF  11300000
#define W2P_OFF  11330000

__device__ __forceinline__ float bfu(u16 u) {
    union { u32 i; float f; } c; c.i = ((u32)u) << 16; return c.f;
}
__device__ __forceinline__ u16 f2bf(float f) {
    union { float f; u32 i; } c; c.f = f;
    u32 r = c.i + 0x7fffu + ((c.i >> 16) & 1u);   // RNE
    return (u16)(r >> 16);
}

// ---------------- zero borders of padded planes ------------------------------
__global__ void zero_borders(u16* __restrict__ x0pn, u16* __restrict__ x1pn) {
    int t = blockIdx.x * 256 + threadIdx.x;       // 202,752
    uint4 z = {0u, 0u, 0u, 0u};
    int cell, v; u16* base; int nch;
    if (t < 67584) { v = t & 7; cell = t >> 3; base = x0pn; nch = 64; }
    else { int u = t - 67584; v = u & 15; cell = u >> 4; base = x1pn; nch = 128; }
    int b = cell / 132, ci = cell - b * 132;
    int y, x;
    if (ci < 34)       { y = 0;       x = ci; }
    else if (ci < 68)  { y = 33;      x = ci - 34; }
    else if (ci < 100) { y = ci - 67; x = 0; }
    else               { y = ci - 99; x = 33; }
    *(uint4*)(base + ((b * 34 + y) * 34 + x) * nch + v * 8) = z;
}

// ---------------- weight pack into B-fragment layouts ------------------------
// B frag: lane l supplies B[k=8*(l>>4)+j][n=l&15], j=0..7.
__global__ void pack_weights(const float* __restrict__ cw1, const float* __restrict__ cw2,
                             u16* __restrict__ w1p, u16* __restrict__ w2p) {
    int t = blockIdx.x * 256 + threadIdx.x;       // 77,824
    if (t < 40960) {
        // w1p[((i0*5+s)*64+lane)*8+j]
        int j = t & 7, lane = (t >> 3) & 63;
        int is = t >> 9, s = is % 5, i0 = is / 5;
        int q = lane & 15;
        int k = 8 * (lane >> 4) + j;              // 0..31
        float v = 0.f;
        if (q < 8 && !(s == 4 && k >= 16)) {
            int tap = (s < 4) ? (2 * s + (k >> 4)) : 8;
            int kk = k & 15;
            int f = 4 * (kk & 3) + (kk >> 2);     // weight row for fan-in slot
            v = cw1[(tap * 16 + f) * 128 + i0 + 16 * q];
        }
        w1p[t] = f2bf(v);
    } else {
        int u = t - 40960;                        // w2p[(((g*9+tap)*2+nt)*64+lane)*8+j]
        int j = u & 7, lane = (u >> 3) & 63;
        int nt = (u >> 9) & 1;
        int gt = u >> 10, tap = gt % 9, g = gt / 9;
        int k = 8 * (lane >> 4) + j;              // fan-in index 0..31
        int f = 4 * (k >> 2) + (k & 3);
        int n = g + 4 * (nt * 16 + (lane & 15));
        w2p[u] = f2bf(cw2[(tap * 32 + f) * 128 + n]);
    }
}

// ---------------- Layer 0: dense conv 3 -> 64, store perm-NHWC bf16 ----------
__global__ __launch_bounds__(256) void l0_kernel(const float* __restrict__ in,
    const float* __restrict__ w, const float* __restrict__ bias, u16* __restrict__ x0pn) {
    int bi = blockIdx.x;
    int cib = bi & 3, rb = (bi >> 2) & 3, b = bi >> 4;
    int t = threadIdx.x, lane = t & 63, wv = t >> 6;
    int col = lane & 31;
    int row = rb * 8 + wv * 2 + (lane >> 5);
    int n0 = cib * 16;

    float acc[16];
#pragma unroll
    for (int k = 0; k < 16; ++k) acc[k] = bias[n0 + k];

    for (int ky = 0; ky < 3; ++ky) {
        int yy = row + ky - 1;
        for (int kx = 0; kx < 3; ++kx) {
            int xx = col + kx - 1;
            if ((unsigned)yy < 32u && (unsigned)xx < 32u) {
                const float* pb = in + ((b * 32 + yy) * 32 + xx) * 3;
                float p0 = pb[0], p1 = pb[1], p2 = pb[2];
                const float* wb = w + (ky * 3 + kx) * 192 + n0;
#pragma unroll
                for (int c = 0; c < 3; ++c) {
                    float pc = (c == 0) ? p0 : ((c == 1) ? p1 : p2);
#pragma unroll
                    for (int k = 0; k < 16; ++k) acc[k] += pc * wb[c * 64 + k];
                }
            }
        }
    }
    // channel c0 = 16*cib + k -> perm 4*k + cib
    u16* ob = x0pn + ((b * 34 + row + 1) * 34 + col + 1) * 64 + cib;
#pragma unroll
    for (int k = 0; k < 16; ++k) ob[4 * k] = f2bf(fmaxf(acc[k], 0.f));
}

// ---------------- Layer 1: MFMA, 16 groups (i0), N=8-in-16 -------------------
__global__ __launch_bounds__(256) void l1_mfma(const u16* __restrict__ x0pn,
    const u16* __restrict__ w1p, const float* __restrict__ cb1, u16* __restrict__ x1pn) {
    int bi = blockIdx.x;                 // b*16 + i0 (same-b adjacent for XCD L2)
    int i0 = bi & 15, b = bi >> 4;
    int t = threadIdx.x, lane = t & 63, wvi = t >> 6;
    int col = lane & 15, grp = lane >> 4;

    int S[4];
#pragma unroll
    for (int m = 0; m < 4; ++m)
        S[m] = (i0 >= 3) ? (i0 - 3 + m) : ((m <= i0) ? m : (12 + m));

    short8v wf[5];
#pragma unroll
    for (int s = 0; s < 5; ++s)
        wf[s] = *(const short8v*)(w1p + ((i0 * 5 + s) * 64 + lane) * 8);

    float bv = (col < 8) ? cb1[i0 + 16 * col] : 0.f;
    const u16* x0b = x0pn + b * (34 * 34 * 64);

    int tq = grp >> 1;                   // tap selector within pair
    int m0 = (grp & 1) * 2;
    int qa0 = 4 * S[m0], qa1 = 4 * S[m0 + 1];

    for (int ti = 0; ti < 16; ++ti) {
        int y = wvi * 8 + (ti >> 1);
        int xb = (ti & 1) * 16;
        f32x4 acc = {bv, bv, bv, bv};
#pragma unroll
        for (int s = 0; s < 4; ++s) {
            int tap = 2 * s + tq;
            int dy = tap / 3, dx = tap % 3;
            const u16* p = x0b + ((y + dy) * 34 + xb + col + dx) * 64;
            union { short8v v; ushort4v h[2]; } A;
            A.h[0] = *(const ushort4v*)(p + qa0);
            A.h[1] = *(const ushort4v*)(p + qa1);
            acc = __builtin_amdgcn_mfma_f32_16x16x32_bf16(A.v, wf[s], acc, 0, 0, 0);
        }
        {   // step 4: tap 8 on k<16 (grp 0,1), zeros elsewhere
            union { short8v v; ushort4v h[2]; } A;
            if (grp < 2) {
                const u16* p = x0b + ((y + 2) * 34 + xb + col + 2) * 64;
                A.h[0] = *(const ushort4v*)(p + 4 * S[grp * 2]);
                A.h[1] = *(const ushort4v*)(p + 4 * S[grp * 2 + 1]);
            } else {
                A.h[0] = (ushort4v)0; A.h[1] = (ushort4v)0;
            }
            acc = __builtin_amdgcn_mfma_f32_16x16x32_bf16(A.v, wf[4], acc, 0, 0, 0);
        }
        if (col < 8) {
            int cperm = (i0 & 3) * 32 + (i0 >> 2) + 4 * col;
            u16* ob = x1pn + (b * 34 + y + 1) * (34 * 128) + cperm;
#pragma unroll
            for (int r = 0; r < 4; ++r) {
                int x = xb + 4 * grp + r;
                ob[(x + 1) * 128] = f2bf(fmaxf(acc[r], 0.f));
            }
        }
    }
}

// ---------------- Layer 2: MFMA, 4 dense 32->32 convs ------------------------
__global__ __launch_bounds__(256) void l2_mfma(const u16* __restrict__ x1pn,
    const u16* __restrict__ w2p, const float* __restrict__ cb2, u16* __restrict__ x2b) {
    int bi = blockIdx.x;                 // b*8 + yh*4 + g
    int g = bi & 3, yh = (bi >> 2) & 1, b = bi >> 3;
    int t = threadIdx.x, lane = t & 63, wvi = t >> 6;
    int col = lane & 15, grp = lane >> 4;

    short8v wf[9][2];
#pragma unroll
    for (int tap = 0; tap < 9; ++tap)
#pragma unroll
        for (int nt = 0; nt < 2; ++nt)
            wf[tap][nt] = *(const short8v*)(w2p + (((g * 9 + tap) * 2 + nt) * 64 + lane) * 8);

    float bv0 = cb2[g + 4 * col];
    float bv1 = cb2[g + 4 * (16 + col)];
    const u16* x1b = x1pn + b * (34 * 34 * 128);

    for (int ri = 0; ri < 4; ++ri) {
        int y = yh * 16 + wvi * 4 + ri;
        f32x4 acc[2][2];
        acc[0][0] = (f32x4){bv0, bv0, bv0, bv0}; acc[0][1] = (f32x4){bv1, bv1, bv1, bv1};
        acc[1][0] = acc[0][0];                   acc[1][1] = acc[0][1];
#pragma unroll
        for (int tap = 0; tap < 9; ++tap) {
            const int dy = tap / 3, dx = tap % 3;
#pragma unroll
            for (int ms = 0; ms < 2; ++ms) {
                short8v a = *(const short8v*)(x1b + ((y + dy) * 34 + ms * 16 + col + dx) * 128
                                              + g * 32 + 8 * grp);
                acc[ms][0] = __builtin_amdgcn_mfma_f32_16x16x32_bf16(a, wf[tap][0], acc[ms][0], 0, 0, 0);
                acc[ms][1] = __builtin_amdgcn_mfma_f32_16x16x32_bf16(a, wf[tap][1], acc[ms][1], 0, 0, 0);
            }
        }
#pragma unroll
        for (int ms = 0; ms < 2; ++ms)
#pragma unroll
            for (int nt = 0; nt < 2; ++nt) {
                int n = g + 4 * (nt * 16 + col);
#pragma unroll
                for (int r = 0; r < 4; ++r) {
                    int x = ms * 16 + 4 * grp + r;
                    x2b[((b * 32 + y) * 32 + x) * 128 + n] = f2bf(fmaxf(acc[ms][nt][r], 0.f));
                }
            }
    }
}

// ---------------- Dense 1 (x2 bf16) + reduce + dense 2 -----------------------
#define D1_NB 512
#define D1_KPB 256
#define D1_SUB 128
__global__ __launch_bounds__(320) void d1_kernel(const u16* __restrict__ x2b,
                                                 const float* __restrict__ dw1,
                                                 float* __restrict__ partial) {
    __shared__ float XT[D1_SUB][65];
    int t = threadIdx.x;
    int b = t & 63;
    int jg = __builtin_amdgcn_readfirstlane(t >> 6);
    float acc[10];
#pragma unroll
    for (int jj = 0; jj < 10; ++jj) acc[jj] = 0.f;

    for (int r = 0; r < D1_KPB / D1_SUB; ++r) {
        int k0 = blockIdx.x * D1_KPB + r * D1_SUB;
        __syncthreads();
        for (int u = t; u < 64 * D1_SUB; u += 320) {
            int bb = u >> 7;
            int i  = u & (D1_SUB - 1);
            XT[i][bb] = bfu(x2b[bb * 131072 + k0 + i]);
        }
        __syncthreads();
        for (int k = 0; k < D1_SUB; ++k) {
            float xv = XT[k][b];
            const float* wr = dw1 + (k0 + k) * 50 + jg * 10;
#pragma unroll
            for (int jj = 0; jj < 10; ++jj)
                acc[jj] += xv * wr[jj];
        }
    }
    float* po = partial + blockIdx.x * 3200 + jg * 640 + b;
#pragma unroll
    for (int jj = 0; jj < 10; ++jj) po[jj * 64] = acc[jj];
}

__global__ void d1_reduce(const float* __restrict__ partial, float* __restrict__ h) {
    int t = blockIdx.x * blockDim.x + threadIdx.x;
    if (t >= 3200) return;
    float s0 = 0.f, s1 = 0.f, s2 = 0.f, s3 = 0.f;
    for (int cb = 0; cb < D1_NB; cb += 4) {
        s0 += partial[(cb + 0) * 3200 + t];
        s1 += partial[(cb + 1) * 3200 + t];
        s2 += partial[(cb + 2) * 3200 + t];
        s3 += partial[(cb + 3) * 3200 + t];
    }
    h[t] = (s0 + s1) + (s2 + s3);
}

__global__ void d2_kernel(const float* __restrict__ h, const float* __restrict__ db1,
                          const float* __restrict__ dw2, const float* __restrict__ db2,
                          float* __restrict__ out) {
    int b = threadIdx.x;
    float a[10];
#pragma unroll
    for (int j = 0; j < 10; ++j) a[j] = db2[j];
    for (int i = 0; i < 50; ++i) {
        float v = fmaxf(h[i * 64 + b] + db1[i], 0.f);
#pragma unroll
        for (int j = 0; j < 10; ++j) a[j] += v * dw2[i * 10 + j];
    }
    float mx = a[0];
#pragma unroll
    for (int j = 1; j < 10; ++j) mx = fmaxf(mx, a[j]);
    float s = 0.f;
#pragma unroll
    for (int j = 0; j < 10; ++j) { a[j] = expf(a[j] - mx); s += a[j]; }
    float inv = 1.f / s;
#pragma unroll
    for (int j = 0; j < 10; ++j) out[b * 10 + j] = a[j] * inv;
}

// -----------------------------------------------------------------------------
extern "C" void kernel_launch(void* const* d_in, const int* in_sizes, int n_in,
                              void* d_out, int out_size, void* d_ws, size_t ws_size,
                              hipStream_t stream) {
    const float* inputs = (const float*)d_in[0];
    const float* cw0 = (const float*)d_in[1];
    const float* cb0 = (const float*)d_in[2];
    const float* cw1 = (const float*)d_in[3];
    const float* cb1 = (const float*)d_in[4];
    const float* cw2 = (const float*)d_in[5];
    const float* cb2 = (const float*)d_in[6];
    const float* dw1 = (const float*)d_in[7];
    const float* db1 = (const float*)d_in[8];
    const float* dw2 = (const float*)d_in[9];
    const float* db2 = (const float*)d_in[10];
    float* out = (float*)d_out;

    float* ws = (float*)d_ws;
    u16* x1pn = (u16*)ws;
    u16* x0pn = (u16*)(ws + X0PN_OFF);
    u16* x2b  = (u16*)(ws + X2B_OFF);
    float* partial = ws;
    float* h  = ws + H_OFF;
    u16* w1p  = (u16*)(ws + W1P_OFF);
    u16* w2p  = (u16*)(ws + W2P_OFF);

    zero_borders<<<792, 256, 0, stream>>>(x0pn, x1pn);
    pack_weights<<<304, 256, 0, stream>>>(cw1, cw2, w1p, w2p);
    l0_kernel<<<1024, 256, 0, stream>>>(inputs, cw0, cb0, x0pn);
    l1_mfma<<<1024, 256, 0, stream>>>(x0pn, w1p, cb1, x1pn);
    l2_mfma<<<512, 256, 0, stream>>>(x1pn, w2p, cb2, x2b);
    d1_kernel<<<D1_NB, 320, 0, stream>>>(x2b, dw1, partial);
    d1_reduce<<<13, 256, 0, stream>>>(partial, h);
    d2_kernel<<<1, 64, 0, stream>>>(h, db1, dw2, db2, out);
}

// Round 6
// 107.204 us; speedup vs baseline: 3.3432x; 2.0098x over previous
//
#include <hip/hip_runtime.h>
#include <math.h>

typedef unsigned short u16;
typedef unsigned int u32;
typedef __attribute__((ext_vector_type(8))) short short8v;    // 8 bf16 (4 VGPR)
typedef __attribute__((ext_vector_type(4))) unsigned short ushort4v;
typedef __attribute__((ext_vector_type(4))) float f32x4;

// ---------------------------------------------------------------------------
// ws layout (f32 units):
//   x1pn [b][34][34][128] bf16 @ 0          (4,734,976 f32)
//   x0pn [b][34][34][64]  bf16 @ 4,734,976  (2,367,488 f32)
//   x2b  [b][32][32][128] bf16 @ 7,102,464  (4,194,304 f32)
//   partial [512][4096] f32 @ 0 (over dead x1pn, 2,097,152)
//   h2 [64][64] f32 @ 2,200,000
//   w1q bf16 @ 11,300,000 (36,864 u16), w2p bf16 @ 11,330,000 (36,864 u16)
// Peak ~45.4 MB.
// ---------------------------------------------------------------------------
#define X0PN_OFF 4734976
#define X2B_OFF  7102464
#define H2_OFF   2200000
#define W1Q_OFF  11300000
#define W2P_OFF  11330000

__device__ __forceinline__ float bfu(u16 u) {
    union { u32 i; float f; } c; c.i = ((u32)u) << 16; return c.f;
}
__device__ __forceinline__ u16 f2bf(float f) {
    union { float f; u32 i; } c; c.f = f;
    u32 r = c.i + 0x7fffu + ((c.i >> 16) & 1u);   // RNE
    return (u16)(r >> 16);
}
__device__ __forceinline__ int Sf(int i0, int m) {
    return (i0 >= 3) ? (i0 - 3 + m) : ((m <= i0) ? m : (12 + m));
}

// ---------------- zero borders of padded planes ------------------------------
__global__ void zero_borders(u16* __restrict__ x0pn, u16* __restrict__ x1pn) {
    int t = blockIdx.x * 256 + threadIdx.x;       // 202,752
    uint4 z = {0u, 0u, 0u, 0u};
    int cell, v; u16* base; int nch;
    if (t < 67584) { v = t & 7; cell = t >> 3; base = x0pn; nch = 64; }
    else { int u = t - 67584; v = u & 15; cell = u >> 4; base = x1pn; nch = 128; }
    int b = cell / 132, ci = cell - b * 132;
    int y, x;
    if (ci < 34)       { y = 0;       x = ci; }
    else if (ci < 68)  { y = 33;      x = ci - 34; }
    else if (ci < 100) { y = ci - 67; x = 0; }
    else               { y = ci - 99; x = 33; }
    *(uint4*)(base + ((b * 34 + y) * 34 + x) * nch + v * 8) = z;
}

// ---------------- weight pack into B-fragment layouts ------------------------
// B frag: lane l supplies B[k=8*(l>>4)+j][n=l&15], j=0..7.
__global__ void pack_weights(const float* __restrict__ cw1, const float* __restrict__ cw2,
                             u16* __restrict__ w1q, u16* __restrict__ w2p) {
    int t = blockIdx.x * 256 + threadIdx.x;       // 73,728
    if (t < 36864) {
        // w1q[((pr*9+tap)*64+lane)*8+j]: pair pr = (i0a=2pr, i0b=2pr+1)
        // n<8  -> group a, k<16 active;  n>=8 -> group b, k>=16 active.
        int j = t & 7, lane = (t >> 3) & 63;
        int tp = t >> 9;                  // pr*9 + tap
        int tap = tp % 9, pr = tp / 9;
        int n = lane & 15;
        int k = 8 * (lane >> 4) + j;
        float v = 0.f;
        if (n < 8) {
            if (k < 16) {
                int f = 4 * (k & 3) + (k >> 2);
                v = cw1[(tap * 16 + f) * 128 + 2 * pr + 16 * n];
            }
        } else {
            if (k >= 16) {
                int k2 = k - 16;
                int f = 4 * (k2 & 3) + (k2 >> 2);
                v = cw1[(tap * 16 + f) * 128 + 2 * pr + 1 + 16 * (n - 8)];
            }
        }
        w1q[t] = f2bf(v);
    } else {
        int u = t - 36864;                // w2p[(((g*9+tap)*2+nt)*64+lane)*8+j]
        int j = u & 7, lane = (u >> 3) & 63;
        int nt = (u >> 9) & 1;
        int gt = u >> 10, tap = gt % 9, g = gt / 9;
        int k = 8 * (lane >> 4) + j;
        int f = 4 * (k >> 2) + (k & 3);
        int n = g + 4 * (nt * 16 + (lane & 15));
        w2p[u] = f2bf(cw2[(tap * 32 + f) * 128 + n]);
    }
}

// ---------------- Layer 0: dense conv 3 -> 64, store perm-NHWC bf16 ----------
__global__ __launch_bounds__(256) void l0_kernel(const float* __restrict__ in,
    const float* __restrict__ w, const float* __restrict__ bias, u16* __restrict__ x0pn) {
    int bi = blockIdx.x;
    int cib = bi & 3, rb = (bi >> 2) & 3, b = bi >> 4;
    int t = threadIdx.x, lane = t & 63, wv = t >> 6;
    int col = lane & 31;
    int row = rb * 8 + wv * 2 + (lane >> 5);
    int n0 = cib * 16;

    float acc[16];
#pragma unroll
    for (int k = 0; k < 16; ++k) acc[k] = bias[n0 + k];

    for (int ky = 0; ky < 3; ++ky) {
        int yy = row + ky - 1;
        for (int kx = 0; kx < 3; ++kx) {
            int xx = col + kx - 1;
            if ((unsigned)yy < 32u && (unsigned)xx < 32u) {
                const float* pb = in + ((b * 32 + yy) * 32 + xx) * 3;
                float p0 = pb[0], p1 = pb[1], p2 = pb[2];
                const float* wb = w + (ky * 3 + kx) * 192 + n0;
#pragma unroll
                for (int c = 0; c < 3; ++c) {
                    float pc = (c == 0) ? p0 : ((c == 1) ? p1 : p2);
#pragma unroll
                    for (int k = 0; k < 16; ++k) acc[k] += pc * wb[c * 64 + k];
                }
            }
        }
    }
    // channel c0 = 16*cib + k -> perm 4*k + cib
    u16* ob = x0pn + ((b * 34 + row + 1) * 34 + col + 1) * 64 + cib;
#pragma unroll
    for (int k = 0; k < 16; ++k) ob[4 * k] = f2bf(fmaxf(acc[k], 0.f));
}

// ---------------- Layer 1: MFMA, i0-paired, LDS-staged, XOR-swizzled --------
__global__ __launch_bounds__(256) void l1_mfma(const u16* __restrict__ x0pn,
    const u16* __restrict__ w1q, const float* __restrict__ cb1, u16* __restrict__ x1pn) {
    __shared__ __align__(16) unsigned char x0s[26112];   // 6 rows x 34 x 64ch bf16
    int bi = blockIdx.x;                 // 512; XCD-swizzled decomposition
    int xcd = bi & 7, slot = bi >> 3;
    int b = xcd * 8 + (slot >> 3), rq = slot & 7;
    int t = threadIdx.x, lane = t & 63, wv = t >> 6;

    {   // stage rows 4rq..4rq+5 (padded coords), swizzled
        const u16* src = x0pn + (size_t)(b * 1156 + rq * 136) * 64;
        for (int c = t; c < 1632; c += 256) {
            uint4 v = *(const uint4*)(src + c * 8);
            int p = c >> 3;
            int dst = (c * 16) ^ ((p & 7) << 4);
            *(uint4*)(x0s + dst) = v;
        }
    }
    __syncthreads();

    int col = lane & 15, khi = lane >> 4;

    for (int pp = 0; pp < 2; ++pp) {
        int pr = wv * 2 + pp;            // i0-pair 0..7
        int i0a = 2 * pr, i0b = 2 * pr + 1;
        int i0g = (khi >= 2) ? i0b : i0a;
        int mb = 2 * (khi & 1);
        int o0 = 8 * Sf(i0g, mb), o1 = 8 * Sf(i0g, mb + 1);

        short8v wf[9];
#pragma unroll
        for (int tap = 0; tap < 9; ++tap)
            wf[tap] = *(const short8v*)(w1q + ((pr * 9 + tap) * 64 + lane) * 8);

        int node = (col < 8) ? (i0a + 16 * col) : (i0b + 16 * (col - 8));
        float bv = cb1[node];
        int cperm = 32 * (node & 3) + (node >> 2);

        for (int mt = 0; mt < 8; ++mt) {
            int row_l = mt >> 1, cbase = (mt & 1) * 16;
            f32x4 acc = {bv, bv, bv, bv};
            int pbase = row_l * 34 + cbase + col;
#pragma unroll
            for (int tap = 0; tap < 9; ++tap) {
                const int dy = tap / 3, dx = tap % 3;
                int p = pbase + dy * 34 + dx;
                int sw = (p & 7) << 4;
                int base = p * 128;
                union { short8v v; uint2 h[2]; } A;
                A.h[0] = *(const uint2*)(x0s + base + (o0 ^ sw));
                A.h[1] = *(const uint2*)(x0s + base + (o1 ^ sw));
                acc = __builtin_amdgcn_mfma_f32_16x16x32_bf16(A.v, wf[tap], acc, 0, 0, 0);
            }
            int prow = rq * 4 + row_l + 1;
            u16* ob = x1pn + ((size_t)(b * 34 + prow) * 34) * 128 + cperm;
#pragma unroll
            for (int r = 0; r < 4; ++r) {
                int pcol = cbase + khi * 4 + r + 1;
                ob[pcol * 128] = f2bf(fmaxf(acc[r], 0.f));
            }
        }
    }
}

// ---------------- Layer 2: MFMA, 4 dense 32->32 convs, XCD-swizzled ----------
__global__ __launch_bounds__(256) void l2_mfma(const u16* __restrict__ x1pn,
    const u16* __restrict__ w2p, const float* __restrict__ cb2, u16* __restrict__ x2b) {
    int bi = blockIdx.x;                 // 512; XCD-swizzled
    int xcd = bi & 7, slot = bi >> 3;
    int b = xcd * 8 + (slot >> 3);
    int rem = slot & 7;
    int g = rem & 3, yh = rem >> 2;
    int t = threadIdx.x, lane = t & 63, wvi = t >> 6;
    int col = lane & 15, grp = lane >> 4;

    short8v wf[9][2];
#pragma unroll
    for (int tap = 0; tap < 9; ++tap)
#pragma unroll
        for (int nt = 0; nt < 2; ++nt)
            wf[tap][nt] = *(const short8v*)(w2p + (((g * 9 + tap) * 2 + nt) * 64 + lane) * 8);

    float bv0 = cb2[g + 4 * col];
    float bv1 = cb2[g + 4 * (16 + col)];
    const u16* x1b = x1pn + b * (34 * 34 * 128);

    for (int ri = 0; ri < 4; ++ri) {
        int y = yh * 16 + wvi * 4 + ri;
        f32x4 acc[2][2];
        acc[0][0] = (f32x4){bv0, bv0, bv0, bv0}; acc[0][1] = (f32x4){bv1, bv1, bv1, bv1};
        acc[1][0] = acc[0][0];                   acc[1][1] = acc[0][1];
#pragma unroll
        for (int tap = 0; tap < 9; ++tap) {
            const int dy = tap / 3, dx = tap % 3;
#pragma unroll
            for (int ms = 0; ms < 2; ++ms) {
                short8v a = *(const short8v*)(x1b + ((y + dy) * 34 + ms * 16 + col + dx) * 128
                                              + g * 32 + 8 * grp);
                acc[ms][0] = __builtin_amdgcn_mfma_f32_16x16x32_bf16(a, wf[tap][0], acc[ms][0], 0, 0, 0);
                acc[ms][1] = __builtin_amdgcn_mfma_f32_16x16x32_bf16(a, wf[tap][1], acc[ms][1], 0, 0, 0);
            }
        }
#pragma unroll
        for (int ms = 0; ms < 2; ++ms)
#pragma unroll
            for (int nt = 0; nt < 2; ++nt) {
                int n = g + 4 * (nt * 16 + col);
#pragma unroll
                for (int r = 0; r < 4; ++r) {
                    int x = ms * 16 + 4 * grp + r;
                    x2b[((b * 32 + y) * 32 + x) * 128 + n] = f2bf(fmaxf(acc[ms][nt][r], 0.f));
                }
            }
    }
}

// ---------------- Dense 1 as MFMA GEMM: [64 x 131072] x [131072 x 50] --------
#define D1_NB 512
__global__ __launch_bounds__(256) void d1_mfma(const u16* __restrict__ x2b,
                                               const float* __restrict__ dw1,
                                               float* __restrict__ partial) {
    int kb = blockIdx.x;                 // K-chunk of 256
    int t = threadIdx.x, lane = t & 63, w = t >> 6;
    int col = lane & 15, khi = lane >> 4;
    int n = 16 * w + col;                // output column (50 valid of 64)
    f32x4 acc[4];
#pragma unroll
    for (int m = 0; m < 4; ++m) acc[m] = (f32x4){0.f, 0.f, 0.f, 0.f};

    int k0 = kb * 256;
#pragma unroll 2
    for (int ks = 0; ks < 8; ++ks) {
        int kbase = k0 + ks * 32 + 8 * khi;
        union { short8v v; u16 e[8]; } Bf;
        if (n < 50) {
            const float* wp = dw1 + (size_t)kbase * 50 + n;
#pragma unroll
            for (int j = 0; j < 8; ++j) Bf.e[j] = f2bf(wp[j * 50]);
        } else {
            Bf.v = (short8v)0;
        }
#pragma unroll
        for (int m = 0; m < 4; ++m) {
            short8v A = *(const short8v*)(x2b + (size_t)(m * 16 + col) * 131072 + kbase);
            acc[m] = __builtin_amdgcn_mfma_f32_16x16x32_bf16(A, Bf.v, acc[m], 0, 0, 0);
        }
    }
    float* po = partial + kb * 4096;
#pragma unroll
    for (int m = 0; m < 4; ++m)
#pragma unroll
        for (int r = 0; r < 4; ++r)
            po[(m * 16 + khi * 4 + r) * 64 + n] = acc[m][r];
}

// ---------------- Dense 1 reduce: sum 512 partials ---------------------------
__global__ void d1_reduce(const float* __restrict__ partial, float* __restrict__ h2) {
    int t = blockIdx.x * blockDim.x + threadIdx.x;   // 4096
    float s0 = 0.f, s1 = 0.f, s2 = 0.f, s3 = 0.f;
    for (int cb = 0; cb < D1_NB; cb += 4) {
        s0 += partial[(cb + 0) * 4096 + t];
        s1 += partial[(cb + 1) * 4096 + t];
        s2 += partial[(cb + 2) * 4096 + t];
        s3 += partial[(cb + 3) * 4096 + t];
    }
    h2[t] = (s0 + s1) + (s2 + s3);       // layout [b][64]
}

// ---------------- Dense 2 + softmax ------------------------------------------
__global__ void d2_kernel(const float* __restrict__ h2, const float* __restrict__ db1,
                          const float* __restrict__ dw2, const float* __restrict__ db2,
                          float* __restrict__ out) {
    int b = threadIdx.x;
    float a[10];
#pragma unroll
    for (int j = 0; j < 10; ++j) a[j] = db2[j];
    for (int i = 0; i < 50; ++i) {
        float v = fmaxf(h2[b * 64 + i] + db1[i], 0.f);
#pragma unroll
        for (int j = 0; j < 10; ++j) a[j] += v * dw2[i * 10 + j];
    }
    float mx = a[0];
#pragma unroll
    for (int j = 1; j < 10; ++j) mx = fmaxf(mx, a[j]);
    float s = 0.f;
#pragma unroll
    for (int j = 0; j < 10; ++j) { a[j] = expf(a[j] - mx); s += a[j]; }
    float inv = 1.f / s;
#pragma unroll
    for (int j = 0; j < 10; ++j) out[b * 10 + j] = a[j] * inv;
}

// -----------------------------------------------------------------------------
extern "C" void kernel_launch(void* const* d_in, const int* in_sizes, int n_in,
                              void* d_out, int out_size, void* d_ws, size_t ws_size,
                              hipStream_t stream) {
    const float* inputs = (const float*)d_in[0];
    const float* cw0 = (const float*)d_in[1];
    const float* cb0 = (const float*)d_in[2];
    const float* cw1 = (const float*)d_in[3];
    const float* cb1 = (const float*)d_in[4];
    const float* cw2 = (const float*)d_in[5];
    const float* cb2 = (const float*)d_in[6];
    const float* dw1 = (const float*)d_in[7];
    const float* db1 = (const float*)d_in[8];
    const float* dw2 = (const float*)d_in[9];
    const float* db2 = (const float*)d_in[10];
    float* out = (float*)d_out;

    float* ws = (float*)d_ws;
    u16* x1pn = (u16*)ws;
    u16* x0pn = (u16*)(ws + X0PN_OFF);
    u16* x2b  = (u16*)(ws + X2B_OFF);
    float* partial = ws;                  // over dead x1pn (8 MB < 18.9 MB)
    float* h2 = ws + H2_OFF;
    u16* w1q  = (u16*)(ws + W1Q_OFF);
    u16* w2p  = (u16*)(ws + W2P_OFF);

    zero_borders<<<792, 256, 0, stream>>>(x0pn, x1pn);
    pack_weights<<<288, 256, 0, stream>>>(cw1, cw2, w1q, w2p);
    l0_kernel<<<1024, 256, 0, stream>>>(inputs, cw0, cb0, x0pn);
    l1_mfma<<<512, 256, 0, stream>>>(x0pn, w1q, cb1, x1pn);
    l2_mfma<<<512, 256, 0, stream>>>(x1pn, w2p, cb2, x2b);
    d1_mfma<<<D1_NB, 256, 0, stream>>>(x2b, dw1, partial);
    d1_reduce<<<16, 256, 0, stream>>>(partial, h2);
    d2_kernel<<<1, 64, 0, stream>>>(h2, db1, dw2, db2, out);
}